// Round 1
// baseline (5064.397 us; speedup 1.0000x reference)
//
#include <hip/hip_runtime.h>
#include <math.h>

// Problem constants
#define TOK   16384      // B*L
#define DMODEL 1024
#define H3    3072       // 3*D
#define LSEQ  8192

// ---------------------------------------------------------------------------
// SGEMM (NT): C[M,N] = beta*C + scale*(A[M,K] @ W[N,K]^T + bias[N])
// 128x128 tile, BK=16, 256 threads, 8x8 micro-tile.
// ---------------------------------------------------------------------------
__global__ __launch_bounds__(256) void sgemm_nt(
    const float* __restrict__ A, const float* __restrict__ W,
    const float* __restrict__ bias, float* __restrict__ C,
    int M, int N, int K, float scale, int beta)
{
    __shared__ float As[16][132];   // k-major, pad to 132 for bank spread
    __shared__ float Bs[16][132];

    const int tid = threadIdx.x;
    const int tx = tid & 15, ty = tid >> 4;
    const int m0 = blockIdx.y * 128;
    const int n0 = blockIdx.x * 128;

    const int lr = tid >> 2;        // 0..63 (row within half-tile)
    const int lk = (tid & 3) * 4;   // 0,4,8,12 (k offset)

    float acc[8][8];
#pragma unroll
    for (int i = 0; i < 8; ++i)
#pragma unroll
        for (int j = 0; j < 8; ++j) acc[i][j] = 0.f;

    for (int k0 = 0; k0 < K; k0 += 16) {
#pragma unroll
        for (int half = 0; half < 2; ++half) {
            int r = lr + half * 64;
            const float4 av = *(const float4*)(&A[(size_t)(m0 + r) * K + k0 + lk]);
            As[lk + 0][r] = av.x; As[lk + 1][r] = av.y;
            As[lk + 2][r] = av.z; As[lk + 3][r] = av.w;
            const float4 bv = *(const float4*)(&W[(size_t)(n0 + r) * K + k0 + lk]);
            Bs[lk + 0][r] = bv.x; Bs[lk + 1][r] = bv.y;
            Bs[lk + 2][r] = bv.z; Bs[lk + 3][r] = bv.w;
        }
        __syncthreads();
#pragma unroll
        for (int kk = 0; kk < 16; ++kk) {
            float a[8], b[8];
#pragma unroll
            for (int i = 0; i < 4; ++i) {
                a[i]     = As[kk][ty * 4 + i];
                a[i + 4] = As[kk][64 + ty * 4 + i];
                b[i]     = Bs[kk][tx * 4 + i];
                b[i + 4] = Bs[kk][64 + tx * 4 + i];
            }
#pragma unroll
            for (int i = 0; i < 8; ++i)
#pragma unroll
                for (int j = 0; j < 8; ++j)
                    acc[i][j] += a[i] * b[j];
        }
        __syncthreads();
    }

#pragma unroll
    for (int i = 0; i < 8; ++i) {
        int rm = m0 + ((i < 4) ? (ty * 4 + i) : (64 + ty * 4 + i - 4));
#pragma unroll
        for (int j = 0; j < 8; ++j) {
            int cn = n0 + ((j < 4) ? (tx * 4 + j) : (64 + tx * 4 + j - 4));
            float v = scale * (acc[i][j] + bias[cn]);
            size_t idx = (size_t)rm * N + cn;
            C[idx] = beta ? (C[idx] + v) : v;
        }
    }
}

// ---------------------------------------------------------------------------
// Flash-style segment attention, fp32.
// One block = one (64-row Q tile, head, segment-instance). S=512, hd=64.
// qkv layout: [token][3072] with Q at h*64, K at 1024+h*64, V at 2048+h*64.
// ao layout: [token][1024], head h at cols h*64..h*64+63.
// Segment tokens: token(i) = base + i*stride,
//   base = batch*LSEQ + parity + seg*512*stride.
// ---------------------------------------------------------------------------
__global__ __launch_bounds__(256) void attn_seg(
    const float* __restrict__ qkv, float* __restrict__ ao,
    int stride, int segs_per_batch)
{
    __shared__ float Qs[64][65];
    __shared__ float Ks[64][65];
    __shared__ float Vs[64][65];
    __shared__ float Ss[64][65];
    __shared__ float mrow[64], lrow[64], arow[64];

    const int tid = threadIdx.x;
    const int tx = tid & 15, ty = tid >> 4;
    const int h  = blockIdx.y;
    const int qt = blockIdx.x;

    const int inst = blockIdx.z;
    const int per_par = 2 * segs_per_batch;     // B * segs_per_batch
    const int p     = inst / per_par;
    const int rem   = inst % per_par;
    const int batch = rem / segs_per_batch;
    const int seg   = rem % segs_per_batch;
    const long base = (long)batch * LSEQ + p + (long)seg * 512 * stride;

    const int qoff = h * 64, koff = 1024 + h * 64, voff = 2048 + h * 64;

    // load Q tile (rows qt*64 .. qt*64+63)
    {
        int r  = tid >> 2;
        int c0 = (tid & 3) * 16;
        long tok = base + (long)(qt * 64 + r) * stride;
        const float* qp = qkv + tok * H3 + qoff;
#pragma unroll
        for (int i = 0; i < 4; ++i) {
            float4 v = *(const float4*)(qp + c0 + i * 4);
            Qs[r][c0 + i * 4 + 0] = v.x; Qs[r][c0 + i * 4 + 1] = v.y;
            Qs[r][c0 + i * 4 + 2] = v.z; Qs[r][c0 + i * 4 + 3] = v.w;
        }
    }
    if (tid < 64) { mrow[tid] = -INFINITY; lrow[tid] = 0.f; }

    float o[4][4];
#pragma unroll
    for (int i = 0; i < 4; ++i)
#pragma unroll
        for (int j = 0; j < 4; ++j) o[i][j] = 0.f;
    __syncthreads();

    for (int kt = 0; kt < 8; ++kt) {
        // load K,V tile
        {
            int r  = tid >> 2;
            int c0 = (tid & 3) * 16;
            long tok = base + (long)(kt * 64 + r) * stride;
            const float* kp = qkv + tok * H3 + koff;
            const float* vp = qkv + tok * H3 + voff;
#pragma unroll
            for (int i = 0; i < 4; ++i) {
                float4 v = *(const float4*)(kp + c0 + i * 4);
                Ks[r][c0 + i*4 + 0] = v.x; Ks[r][c0 + i*4 + 1] = v.y;
                Ks[r][c0 + i*4 + 2] = v.z; Ks[r][c0 + i*4 + 3] = v.w;
                float4 w = *(const float4*)(vp + c0 + i * 4);
                Vs[r][c0 + i*4 + 0] = w.x; Vs[r][c0 + i*4 + 1] = w.y;
                Vs[r][c0 + i*4 + 2] = w.z; Vs[r][c0 + i*4 + 3] = w.w;
            }
        }
        __syncthreads();

        // S = (Q K^T) * 0.125
        float s[4][4];
#pragma unroll
        for (int i = 0; i < 4; ++i)
#pragma unroll
            for (int j = 0; j < 4; ++j) s[i][j] = 0.f;
#pragma unroll 8
        for (int kk = 0; kk < 64; ++kk) {
            float a[4], b[4];
#pragma unroll
            for (int i = 0; i < 4; ++i) { a[i] = Qs[ty*4 + i][kk]; b[i] = Ks[tx*4 + i][kk]; }
#pragma unroll
            for (int i = 0; i < 4; ++i)
#pragma unroll
                for (int j = 0; j < 4; ++j) s[i][j] += a[i] * b[j];
        }
#pragma unroll
        for (int i = 0; i < 4; ++i)
#pragma unroll
            for (int j = 0; j < 4; ++j) Ss[ty*4 + i][tx*4 + j] = s[i][j] * 0.125f;
        __syncthreads();

        // online softmax (one thread per Q row)
        if (tid < 64) {
            float mo = mrow[tid];
            float mn = mo;
#pragma unroll 8
            for (int j = 0; j < 64; ++j) mn = fmaxf(mn, Ss[tid][j]);
            float al = __expf(mo - mn);
            float sum = 0.f;
#pragma unroll 8
            for (int j = 0; j < 64; ++j) {
                float pv = __expf(Ss[tid][j] - mn);
                Ss[tid][j] = pv;
                sum += pv;
            }
            mrow[tid] = mn;
            lrow[tid] = lrow[tid] * al + sum;
            arow[tid] = al;
        }
        __syncthreads();

        // O = O*alpha + P V
        float al[4];
#pragma unroll
        for (int i = 0; i < 4; ++i) al[i] = arow[ty*4 + i];
#pragma unroll
        for (int i = 0; i < 4; ++i)
#pragma unroll
            for (int j = 0; j < 4; ++j) o[i][j] *= al[i];
#pragma unroll 8
        for (int kk = 0; kk < 64; ++kk) {
            float pr[4], vv[4];
#pragma unroll
            for (int i = 0; i < 4; ++i) { pr[i] = Ss[ty*4 + i][kk]; vv[i] = Vs[kk][tx*4 + i]; }
#pragma unroll
            for (int i = 0; i < 4; ++i)
#pragma unroll
                for (int j = 0; j < 4; ++j) o[i][j] += pr[i] * vv[j];
        }
        __syncthreads();   // protect Ks/Vs/Ss before next tile; also fences lrow
    }

    float linv[4];
#pragma unroll
    for (int i = 0; i < 4; ++i) linv[i] = 1.f / lrow[ty*4 + i];
#pragma unroll
    for (int i = 0; i < 4; ++i) {
        long tok = base + (long)(qt * 64 + ty * 4 + i) * stride;
        float* op = ao + tok * DMODEL + h * 64 + tx * 4;
#pragma unroll
        for (int j = 0; j < 4; ++j) op[j] = o[i][j] * linv[i];
    }
}

// ---------------------------------------------------------------------------
// Launch: out = (attn_br0(x) + attn_br1(x)) / 3
//   br0: stride 1, 16 segs/batch; br1: stride 2, 8 segs/batch, 2 parities.
// ws: qkv [16384*3072] fp32 (201MB) + ao [16384*1024] fp32 (67MB) = 256 MiB.
// ---------------------------------------------------------------------------
extern "C" void kernel_launch(void* const* d_in, const int* in_sizes, int n_in,
                              void* d_out, int out_size, void* d_ws, size_t ws_size,
                              hipStream_t stream) {
    const float* x    = (const float*)d_in[0];
    const float* Wqkv = (const float*)d_in[1];
    const float* bqkv = (const float*)d_in[2];
    const float* Wout = (const float*)d_in[3];
    const float* bout = (const float*)d_in[4];
    float* out = (float*)d_out;

    float* qkv = (float*)d_ws;
    float* ao  = qkv + (size_t)TOK * H3;

    dim3 blk(256);
    const float third = 1.0f / 3.0f;

    // ---- branch 0 (stride 1) ----
    sgemm_nt<<<dim3(24, 128), blk, 0, stream>>>(x, Wqkv, bqkv, qkv,
                                                TOK, H3, DMODEL, 1.0f, 0);
    attn_seg<<<dim3(8, 16, 32), blk, 0, stream>>>(qkv, ao, 1, 16);
    sgemm_nt<<<dim3(8, 128), blk, 0, stream>>>(ao, Wout, bout, out,
                                               TOK, DMODEL, DMODEL, third, 0);

    // ---- branch 1 (stride 2, parities 0/1) ----
    sgemm_nt<<<dim3(24, 128), blk, 0, stream>>>(x, Wqkv + (size_t)H3 * DMODEL,
                                                bqkv + H3, qkv,
                                                TOK, H3, DMODEL, 1.0f, 0);
    attn_seg<<<dim3(8, 16, 32), blk, 0, stream>>>(qkv, ao, 2, 8);
    sgemm_nt<<<dim3(8, 128), blk, 0, stream>>>(ao, Wout + (size_t)DMODEL * DMODEL,
                                               bout + DMODEL, out,
                                               TOK, DMODEL, DMODEL, third, 1);
}

// Round 2
// 3759.431 us; speedup vs baseline: 1.3471x; 1.3471x over previous
//
#include <hip/hip_runtime.h>
#include <math.h>

#define TOK    16384
#define DMODEL 1024
#define H3     3072
#define LSEQ   8192
#define CHUNK  4096      // tokens per qkv chunk (4 chunks)

typedef unsigned short ushort_t;
using bf16x8 = __attribute__((ext_vector_type(8))) __bf16;
using f32x4  = __attribute__((ext_vector_type(4))) float;

// ---- bf16 helpers (RNE) ----
__device__ __forceinline__ unsigned short f2bf(float f) {
    unsigned int u = __float_as_uint(f);
    u += 0x7FFF + ((u >> 16) & 1);
    return (unsigned short)(u >> 16);
}
__device__ __forceinline__ float bf2f(unsigned short b) {
    return __uint_as_float(((unsigned int)b) << 16);
}

// async global->LDS, 16B per lane, dst = uniform base + lane*16
__device__ __forceinline__ void gld16(const void* g, void* l) {
    __builtin_amdgcn_global_load_lds(
        (const __attribute__((address_space(1))) unsigned int*)g,
        (__attribute__((address_space(3))) unsigned int*)l, 16, 0, 0);
}

// ---------------------------------------------------------------------------
// split fp32 -> (hi, lo) bf16 pair.  n4 = n/4.
// ---------------------------------------------------------------------------
__global__ __launch_bounds__(256) void split_f32(
    const float* __restrict__ s, ushort_t* __restrict__ h,
    ushort_t* __restrict__ l, int n4)
{
    int i = blockIdx.x * 256 + threadIdx.x;
    if (i >= n4) return;
    float4 v = ((const float4*)s)[i];
    ushort4 hp, lp;
    hp.x = f2bf(v.x); lp.x = f2bf(v.x - bf2f(hp.x));
    hp.y = f2bf(v.y); lp.y = f2bf(v.y - bf2f(hp.y));
    hp.z = f2bf(v.z); lp.z = f2bf(v.z - bf2f(hp.z));
    hp.w = f2bf(v.w); lp.w = f2bf(v.w - bf2f(hp.w));
    ((ushort4*)h)[i] = hp;
    ((ushort4*)l)[i] = lp;
}

// ---------------------------------------------------------------------------
// Split-bf16 MFMA GEMM (NT): C[M,N] = beta*C + scale*(A@W^T + bias)
//   A ~ Ah+Al [M,K] bf16, W ~ Wh+Wl [N,K] bf16; 3 passes (hh, lh, hl).
// 128x128 tile, BK=32, 256 thr = 4 waves, 16x16x32 MFMA, 4x4 tiles/wave.
// LDS holds tiles in FRAGMENT layout: frag f = 1KB, lane slot = lane*16B,
// so global_load_lds staging order == ds_read_b128 fragment order.
// ---------------------------------------------------------------------------
__global__ __launch_bounds__(256) void gemm_split_nt(
    const ushort_t* __restrict__ Ah, const ushort_t* __restrict__ Al,
    const ushort_t* __restrict__ Wh, const ushort_t* __restrict__ Wl,
    const float* __restrict__ bias, float* __restrict__ C,
    int M, int N, int K, float scale, int beta)
{
    __shared__ __align__(16) ushort_t As[8 * 512];   // 8 frags x 1KB
    __shared__ __align__(16) ushort_t Bs[8 * 512];

    const int tid  = threadIdx.x;
    const int lane = tid & 63;
    const int w    = tid >> 6;
    const int m0 = blockIdx.y * 128;
    const int n0 = blockIdx.x * 128;

    // ---- staging assignment: waves 0,1 stage A frags 0-3/4-7; waves 2,3 B ----
    const bool isA = (w < 2);
    const int  fb  = (w & 1) * 4;
    const int  blk0 = isA ? m0 : n0;
    long soff[4];
#pragma unroll
    for (int i = 0; i < 4; ++i) {
        int row = blk0 + (fb + i) * 16 + (lane & 15);
        soff[i] = (long)row * K + (lane >> 4) * 8;
    }
    ushort_t* sdst = (isA ? As : Bs) + fb * 512;
    const ushort_t* srcs[3];
    if (isA) { srcs[0] = Ah; srcs[1] = Al; srcs[2] = Ah; }
    else     { srcs[0] = Wh; srcs[1] = Wh; srcs[2] = Wl; }

    // ---- compute assignment: wave -> 64x64 quadrant ----
    const int am0 = (w >> 1) * 4;   // a-frag base
    const int bn0 = (w & 1) * 4;    // b-frag base

    f32x4 acc[4][4];
#pragma unroll
    for (int i = 0; i < 4; ++i)
#pragma unroll
        for (int j = 0; j < 4; ++j) acc[i][j] = (f32x4){0.f, 0.f, 0.f, 0.f};

    for (int p = 0; p < 3; ++p) {
        const ushort_t* S = srcs[p];
        for (int k0 = 0; k0 < K; k0 += 32) {
#pragma unroll
            for (int i = 0; i < 4; ++i)
                gld16(S + soff[i] + k0, sdst + i * 512);
            __syncthreads();
            bf16x8 af[4], bf[4];
#pragma unroll
            for (int i = 0; i < 4; ++i) {
                af[i] = *(const bf16x8*)(As + (am0 + i) * 512 + lane * 8);
                bf[i] = *(const bf16x8*)(Bs + (bn0 + i) * 512 + lane * 8);
            }
#pragma unroll
            for (int i = 0; i < 4; ++i)
#pragma unroll
                for (int j = 0; j < 4; ++j)
                    acc[i][j] = __builtin_amdgcn_mfma_f32_16x16x32_bf16(
                        af[i], bf[j], acc[i][j], 0, 0, 0);
            __syncthreads();
        }
    }

    // ---- epilogue: D row=(lane>>4)*4+reg, col=lane&15 ----
    const int wm = (w >> 1) * 64, wn = (w & 1) * 64;
    const int r0 = (lane >> 4) * 4;
    const int cn = lane & 15;
#pragma unroll
    for (int j = 0; j < 4; ++j) {
        int col = n0 + wn + j * 16 + cn;
        float bv = bias[col];
#pragma unroll
        for (int i = 0; i < 4; ++i) {
            int rowb = m0 + wm + i * 16 + r0;
#pragma unroll
            for (int r = 0; r < 4; ++r) {
                size_t idx = (size_t)(rowb + r) * N + col;
                float v = scale * (acc[i][j][r] + bv);
                C[idx] = beta ? (C[idx] + v) : v;
            }
        }
    }
}

// ---------------------------------------------------------------------------
// Flash-style segment attention, fp32 compute.
// Reads a CHUNK-local qkv buffer; writes output as bf16 hi/lo split pair.
// One block = (64-row Q tile, head, instance). S=512, hd=64.
// instance z: stride1 -> seg z (base z*512); stride2 -> parity z>>2, span z&3.
// ---------------------------------------------------------------------------
__global__ __launch_bounds__(256) void attn_seg(
    const float* __restrict__ qkv, ushort_t* __restrict__ aoh,
    ushort_t* __restrict__ aol, int stride, long tok0)
{
    __shared__ float Qs[64][65];
    __shared__ float Ks[64][65];
    __shared__ float Vs[64][65];
    __shared__ float Ss[64][65];
    __shared__ float mrow[64], lrow[64], arow[64];

    const int tid = threadIdx.x;
    const int tx = tid & 15, ty = tid >> 4;
    const int h  = blockIdx.y;
    const int qt = blockIdx.x;
    const int z  = blockIdx.z;
    const int base_local = (stride == 1) ? z * 512 : ((z >> 2) + (z & 3) * 1024);

    const int qoff = h * 64, koff = 1024 + h * 64, voff = 2048 + h * 64;

    {   // load Q tile
        int r  = tid >> 2;
        int c0 = (tid & 3) * 16;
        long tok = base_local + (long)(qt * 64 + r) * stride;
        const float* qp = qkv + tok * H3 + qoff;
#pragma unroll
        for (int i = 0; i < 4; ++i) {
            float4 v = *(const float4*)(qp + c0 + i * 4);
            Qs[r][c0 + i*4 + 0] = v.x; Qs[r][c0 + i*4 + 1] = v.y;
            Qs[r][c0 + i*4 + 2] = v.z; Qs[r][c0 + i*4 + 3] = v.w;
        }
    }
    if (tid < 64) { mrow[tid] = -INFINITY; lrow[tid] = 0.f; }

    float o[4][4];
#pragma unroll
    for (int i = 0; i < 4; ++i)
#pragma unroll
        for (int j = 0; j < 4; ++j) o[i][j] = 0.f;
    __syncthreads();

    for (int kt = 0; kt < 8; ++kt) {
        {   // load K,V tile
            int r  = tid >> 2;
            int c0 = (tid & 3) * 16;
            long tok = base_local + (long)(kt * 64 + r) * stride;
            const float* kp = qkv + tok * H3 + koff;
            const float* vp = qkv + tok * H3 + voff;
#pragma unroll
            for (int i = 0; i < 4; ++i) {
                float4 v = *(const float4*)(kp + c0 + i * 4);
                Ks[r][c0 + i*4 + 0] = v.x; Ks[r][c0 + i*4 + 1] = v.y;
                Ks[r][c0 + i*4 + 2] = v.z; Ks[r][c0 + i*4 + 3] = v.w;
                float4 u = *(const float4*)(vp + c0 + i * 4);
                Vs[r][c0 + i*4 + 0] = u.x; Vs[r][c0 + i*4 + 1] = u.y;
                Vs[r][c0 + i*4 + 2] = u.z; Vs[r][c0 + i*4 + 3] = u.w;
            }
        }
        __syncthreads();

        float s[4][4];
#pragma unroll
        for (int i = 0; i < 4; ++i)
#pragma unroll
            for (int j = 0; j < 4; ++j) s[i][j] = 0.f;
#pragma unroll 8
        for (int kk = 0; kk < 64; ++kk) {
            float a[4], b[4];
#pragma unroll
            for (int i = 0; i < 4; ++i) { a[i] = Qs[ty*4 + i][kk]; b[i] = Ks[tx*4 + i][kk]; }
#pragma unroll
            for (int i = 0; i < 4; ++i)
#pragma unroll
                for (int j = 0; j < 4; ++j) s[i][j] += a[i] * b[j];
        }
#pragma unroll
        for (int i = 0; i < 4; ++i)
#pragma unroll
            for (int j = 0; j < 4; ++j) Ss[ty*4 + i][tx*4 + j] = s[i][j] * 0.125f;
        __syncthreads();

        if (tid < 64) {
            float mo = mrow[tid];
            float mn = mo;
#pragma unroll 8
            for (int j = 0; j < 64; ++j) mn = fmaxf(mn, Ss[tid][j]);
            float al = __expf(mo - mn);
            float sum = 0.f;
#pragma unroll 8
            for (int j = 0; j < 64; ++j) {
                float pv = __expf(Ss[tid][j] - mn);
                Ss[tid][j] = pv;
                sum += pv;
            }
            mrow[tid] = mn;
            lrow[tid] = lrow[tid] * al + sum;
            arow[tid] = al;
        }
        __syncthreads();

        float al[4];
#pragma unroll
        for (int i = 0; i < 4; ++i) al[i] = arow[ty*4 + i];
#pragma unroll
        for (int i = 0; i < 4; ++i)
#pragma unroll
            for (int j = 0; j < 4; ++j) o[i][j] *= al[i];
#pragma unroll 8
        for (int kk = 0; kk < 64; ++kk) {
            float pr[4], vv[4];
#pragma unroll
            for (int i = 0; i < 4; ++i) { pr[i] = Ss[ty*4 + i][kk]; vv[i] = Vs[kk][tx*4 + i]; }
#pragma unroll
            for (int i = 0; i < 4; ++i)
#pragma unroll
                for (int j = 0; j < 4; ++j) o[i][j] += pr[i] * vv[j];
        }
        __syncthreads();
    }

    float linv[4];
#pragma unroll
    for (int i = 0; i < 4; ++i) linv[i] = 1.f / lrow[ty*4 + i];
#pragma unroll
    for (int i = 0; i < 4; ++i) {
        long gtok = tok0 + base_local + (long)(qt * 64 + ty * 4 + i) * stride;
        size_t off = (size_t)gtok * DMODEL + h * 64 + tx * 4;
#pragma unroll
        for (int j = 0; j < 4; ++j) {
            float val = o[i][j] * linv[i];
            unsigned short hb = f2bf(val);
            aoh[off + j] = hb;
            aol[off + j] = f2bf(val - bf2f(hb));
        }
    }
}

// ---------------------------------------------------------------------------
// out = (attn_br0(x) + attn_br1(x)) / 3,  QKV processed in 4 token-chunks.
// ws layout (201.3 MB total):
//   xh,xl [16384x1024]bf16 | wqh,wql [3072x1024]bf16 | woh,wol [1024x1024]bf16
//   | qkvc [4096x3072]f32 | aoh,aol [16384x1024]bf16
// ---------------------------------------------------------------------------
extern "C" void kernel_launch(void* const* d_in, const int* in_sizes, int n_in,
                              void* d_out, int out_size, void* d_ws, size_t ws_size,
                              hipStream_t stream) {
    const float* x    = (const float*)d_in[0];
    const float* Wqkv = (const float*)d_in[1];
    const float* bqkv = (const float*)d_in[2];
    const float* Wout = (const float*)d_in[3];
    const float* bout = (const float*)d_in[4];
    float* out = (float*)d_out;

    char* wp = (char*)d_ws;
    ushort_t* xh  = (ushort_t*)wp; wp += (size_t)TOK * DMODEL * 2;
    ushort_t* xl  = (ushort_t*)wp; wp += (size_t)TOK * DMODEL * 2;
    ushort_t* wqh = (ushort_t*)wp; wp += (size_t)H3 * DMODEL * 2;
    ushort_t* wql = (ushort_t*)wp; wp += (size_t)H3 * DMODEL * 2;
    ushort_t* woh = (ushort_t*)wp; wp += (size_t)DMODEL * DMODEL * 2;
    ushort_t* wol = (ushort_t*)wp; wp += (size_t)DMODEL * DMODEL * 2;
    float*    qkvc = (float*)wp;   wp += (size_t)CHUNK * H3 * 4;
    ushort_t* aoh = (ushort_t*)wp; wp += (size_t)TOK * DMODEL * 2;
    ushort_t* aol = (ushort_t*)wp;

    dim3 blk(256);
    const float third = 1.0f / 3.0f;

    {   // split x once
        int n4 = TOK * DMODEL / 4;
        split_f32<<<(n4 + 255) / 256, blk, 0, stream>>>(x, xh, xl, n4);
    }

    for (int br = 0; br < 2; ++br) {
        const int stride = (br == 0) ? 1 : 2;
        {   // split this branch's weights
            int n4q = H3 * DMODEL / 4;
            split_f32<<<(n4q + 255) / 256, blk, 0, stream>>>(
                Wqkv + (size_t)br * H3 * DMODEL, wqh, wql, n4q);
            int n4o = DMODEL * DMODEL / 4;
            split_f32<<<(n4o + 255) / 256, blk, 0, stream>>>(
                Wout + (size_t)br * DMODEL * DMODEL, woh, wol, n4o);
        }
        for (int c = 0; c < TOK / CHUNK; ++c) {
            gemm_split_nt<<<dim3(H3 / 128, CHUNK / 128), blk, 0, stream>>>(
                xh + (size_t)c * CHUNK * DMODEL, xl + (size_t)c * CHUNK * DMODEL,
                wqh, wql, bqkv + br * H3, qkvc,
                CHUNK, H3, DMODEL, 1.0f, 0);
            attn_seg<<<dim3(8, 16, 8), blk, 0, stream>>>(
                qkvc, aoh, aol, stride, (long)c * CHUNK);
        }
        gemm_split_nt<<<dim3(DMODEL / 128, TOK / 128), blk, 0, stream>>>(
            aoh, aol, woh, wol, bout + br * DMODEL, out,
            TOK, DMODEL, DMODEL, third, br);
    }
}

// Round 3
// 3147.545 us; speedup vs baseline: 1.6090x; 1.1944x over previous
//
#include <hip/hip_runtime.h>
#include <math.h>

#define TOK    16384
#define DMODEL 1024
#define H3     3072
#define LSEQ   8192
#define CHUNK  8192      // tokens per qkv chunk (2 chunks = batch rows)

typedef unsigned short ushort_t;
using bf16x8 = __attribute__((ext_vector_type(8))) __bf16;
using f32x4  = __attribute__((ext_vector_type(4))) float;

// ---- bf16 helpers (RNE) ----
__device__ __forceinline__ unsigned short f2bf(float f) {
    unsigned int u = __float_as_uint(f);
    u += 0x7FFF + ((u >> 16) & 1);
    return (unsigned short)(u >> 16);
}
__device__ __forceinline__ float bf2f(unsigned short b) {
    return __uint_as_float(((unsigned int)b) << 16);
}

// async global->LDS, 16B per lane, dst = uniform base + lane*16
__device__ __forceinline__ void gld16(const void* g, void* l) {
    __builtin_amdgcn_global_load_lds(
        (const __attribute__((address_space(1))) unsigned int*)g,
        (__attribute__((address_space(3))) unsigned int*)l, 16, 0, 0);
}

// ---------------------------------------------------------------------------
// split fp32 -> (hi, lo) bf16 pair.  n4 = n/4.
// ---------------------------------------------------------------------------
__global__ __launch_bounds__(256) void split_f32(
    const float* __restrict__ s, ushort_t* __restrict__ h,
    ushort_t* __restrict__ l, int n4)
{
    int i = blockIdx.x * 256 + threadIdx.x;
    if (i >= n4) return;
    float4 v = ((const float4*)s)[i];
    ushort4 hp, lp;
    hp.x = f2bf(v.x); lp.x = f2bf(v.x - bf2f(hp.x));
    hp.y = f2bf(v.y); lp.y = f2bf(v.y - bf2f(hp.y));
    hp.z = f2bf(v.z); lp.z = f2bf(v.z - bf2f(hp.z));
    hp.w = f2bf(v.w); lp.w = f2bf(v.w - bf2f(hp.w));
    ((ushort4*)h)[i] = hp;
    ((ushort4*)l)[i] = lp;
}

// ---------------------------------------------------------------------------
// Split-bf16 MFMA GEMM (NT), FUSED 3-term K-loop:
//   C = beta*C + scale*((Ah+Al)@(Wh+Wl)^T + bias), dropping Al*Wl.
// 128x128 tile, BK=32, 256 thr = 4 waves, 16x16x32 MFMA, 4x4 frag-tiles/wave.
// Per k-iter: stage Ah,Al,Bh,Bl tiles (32 KB), 48 MFMAs/wave per barrier.
// LDS in FRAGMENT layout: frag = 1KB, lane slot = lane*16B, so
// global_load_lds order == ds_read_b128 order (bank-conflict-free, R2: 0).
// ---------------------------------------------------------------------------
__global__ __launch_bounds__(256) void gemm_split_nt(
    const ushort_t* __restrict__ Ah, const ushort_t* __restrict__ Al,
    const ushort_t* __restrict__ Wh, const ushort_t* __restrict__ Wl,
    const float* __restrict__ bias, float* __restrict__ C,
    int M, int N, int K, float scale, int beta)
{
    __shared__ __align__(16) ushort_t As[2][8 * 512];   // [hi/lo][frag*512]
    __shared__ __align__(16) ushort_t Bs[2][8 * 512];

    const int tid  = threadIdx.x;
    const int lane = tid & 63;
    const int w    = tid >> 6;
    const int m0 = blockIdx.y * 128;
    const int n0 = blockIdx.x * 128;

    // ---- staging: waves 0,1 -> A frags 0-3/4-7 (hi+lo); waves 2,3 -> B ----
    const bool isA = (w < 2);
    const int  fb  = (w & 1) * 4;
    const int  blk0 = isA ? m0 : n0;
    long soff[4];
#pragma unroll
    for (int i = 0; i < 4; ++i) {
        int row = blk0 + (fb + i) * 16 + (lane & 15);
        soff[i] = (long)row * K + (lane >> 4) * 8;
    }
    ushort_t* dst_h = (isA ? As[0] : Bs[0]) + fb * 512;
    ushort_t* dst_l = (isA ? As[1] : Bs[1]) + fb * 512;
    const ushort_t* src_h = isA ? Ah : Wh;
    const ushort_t* src_l = isA ? Al : Wl;

    // ---- compute: wave -> 64x64 quadrant, 4x4 frags ----
    const int am0 = (w >> 1) * 4;
    const int bn0 = (w & 1) * 4;

    f32x4 acc[4][4];
#pragma unroll
    for (int i = 0; i < 4; ++i)
#pragma unroll
        for (int j = 0; j < 4; ++j) acc[i][j] = (f32x4){0.f, 0.f, 0.f, 0.f};

    for (int k0 = 0; k0 < K; k0 += 32) {
#pragma unroll
        for (int i = 0; i < 4; ++i) {
            gld16(src_h + soff[i] + k0, dst_h + i * 512);
            gld16(src_l + soff[i] + k0, dst_l + i * 512);
        }
        __syncthreads();

        bf16x8 ah[4], al[4], bh[4], bl[4];
#pragma unroll
        for (int i = 0; i < 4; ++i) {
            ah[i] = *(const bf16x8*)(As[0] + (am0 + i) * 512 + lane * 8);
            al[i] = *(const bf16x8*)(As[1] + (am0 + i) * 512 + lane * 8);
            bh[i] = *(const bf16x8*)(Bs[0] + (bn0 + i) * 512 + lane * 8);
            bl[i] = *(const bf16x8*)(Bs[1] + (bn0 + i) * 512 + lane * 8);
        }
#pragma unroll
        for (int i = 0; i < 4; ++i)
#pragma unroll
            for (int j = 0; j < 4; ++j)
                acc[i][j] = __builtin_amdgcn_mfma_f32_16x16x32_bf16(
                    ah[i], bh[j], acc[i][j], 0, 0, 0);
#pragma unroll
        for (int i = 0; i < 4; ++i)
#pragma unroll
            for (int j = 0; j < 4; ++j)
                acc[i][j] = __builtin_amdgcn_mfma_f32_16x16x32_bf16(
                    al[i], bh[j], acc[i][j], 0, 0, 0);
#pragma unroll
        for (int i = 0; i < 4; ++i)
#pragma unroll
            for (int j = 0; j < 4; ++j)
                acc[i][j] = __builtin_amdgcn_mfma_f32_16x16x32_bf16(
                    ah[i], bl[j], acc[i][j], 0, 0, 0);
        __syncthreads();
    }

    // ---- epilogue: D row=(lane>>4)*4+reg, col=lane&15 ----
    const int wm = (w >> 1) * 64, wn = (w & 1) * 64;
    const int r0 = (lane >> 4) * 4;
    const int cn = lane & 15;
#pragma unroll
    for (int j = 0; j < 4; ++j) {
        int col = n0 + wn + j * 16 + cn;
        float bv = bias[col];
#pragma unroll
        for (int i = 0; i < 4; ++i) {
            int rowb = m0 + wm + i * 16 + r0;
#pragma unroll
            for (int r = 0; r < 4; ++r) {
                size_t idx = (size_t)(rowb + r) * N + col;
                float v = scale * (acc[i][j][r] + bv);
                C[idx] = beta ? (C[idx] + v) : v;
            }
        }
    }
}

// ---------------------------------------------------------------------------
// Flash-style segment attention, fp32 compute.
// Reads CHUNK-local (8192-token = one batch row) qkv; writes bf16 hi/lo pair.
// One block = (64-row Q tile, head, instance z). S=512, hd=64.
// z: stride1 -> seg z (base z*512); stride2 -> parity z>>3, span z&7.
// ---------------------------------------------------------------------------
__global__ __launch_bounds__(256) void attn_seg(
    const float* __restrict__ qkv, ushort_t* __restrict__ aoh,
    ushort_t* __restrict__ aol, int stride, long tok0)
{
    __shared__ float Qs[64][65];
    __shared__ float Ks[64][65];
    __shared__ float Vs[64][65];
    __shared__ float Ss[64][65];
    __shared__ float mrow[64], lrow[64], arow[64];

    const int tid = threadIdx.x;
    const int tx = tid & 15, ty = tid >> 4;
    const int h  = blockIdx.y;
    const int qt = blockIdx.x;
    const int z  = blockIdx.z;
    const int base_local = (stride == 1) ? z * 512 : ((z >> 3) + (z & 7) * 1024);

    const int qoff = h * 64, koff = 1024 + h * 64, voff = 2048 + h * 64;

    {   // load Q tile
        int r  = tid >> 2;
        int c0 = (tid & 3) * 16;
        long tok = base_local + (long)(qt * 64 + r) * stride;
        const float* qp = qkv + tok * H3 + qoff;
#pragma unroll
        for (int i = 0; i < 4; ++i) {
            float4 v = *(const float4*)(qp + c0 + i * 4);
            Qs[r][c0 + i*4 + 0] = v.x; Qs[r][c0 + i*4 + 1] = v.y;
            Qs[r][c0 + i*4 + 2] = v.z; Qs[r][c0 + i*4 + 3] = v.w;
        }
    }
    if (tid < 64) { mrow[tid] = -INFINITY; lrow[tid] = 0.f; }

    float o[4][4];
#pragma unroll
    for (int i = 0; i < 4; ++i)
#pragma unroll
        for (int j = 0; j < 4; ++j) o[i][j] = 0.f;
    __syncthreads();

    for (int kt = 0; kt < 8; ++kt) {
        {   // load K,V tile
            int r  = tid >> 2;
            int c0 = (tid & 3) * 16;
            long tok = base_local + (long)(kt * 64 + r) * stride;
            const float* kp = qkv + tok * H3 + koff;
            const float* vp = qkv + tok * H3 + voff;
#pragma unroll
            for (int i = 0; i < 4; ++i) {
                float4 v = *(const float4*)(kp + c0 + i * 4);
                Ks[r][c0 + i*4 + 0] = v.x; Ks[r][c0 + i*4 + 1] = v.y;
                Ks[r][c0 + i*4 + 2] = v.z; Ks[r][c0 + i*4 + 3] = v.w;
                float4 u = *(const float4*)(vp + c0 + i * 4);
                Vs[r][c0 + i*4 + 0] = u.x; Vs[r][c0 + i*4 + 1] = u.y;
                Vs[r][c0 + i*4 + 2] = u.z; Vs[r][c0 + i*4 + 3] = u.w;
            }
        }
        __syncthreads();

        float s[4][4];
#pragma unroll
        for (int i = 0; i < 4; ++i)
#pragma unroll
            for (int j = 0; j < 4; ++j) s[i][j] = 0.f;
#pragma unroll 8
        for (int kk = 0; kk < 64; ++kk) {
            float a[4], b[4];
#pragma unroll
            for (int i = 0; i < 4; ++i) { a[i] = Qs[ty*4 + i][kk]; b[i] = Ks[tx*4 + i][kk]; }
#pragma unroll
            for (int i = 0; i < 4; ++i)
#pragma unroll
                for (int j = 0; j < 4; ++j) s[i][j] += a[i] * b[j];
        }
#pragma unroll
        for (int i = 0; i < 4; ++i)
#pragma unroll
            for (int j = 0; j < 4; ++j) Ss[ty*4 + i][tx*4 + j] = s[i][j] * 0.125f;
        __syncthreads();

        if (tid < 64) {
            float mo = mrow[tid];
            float mn = mo;
#pragma unroll 8
            for (int j = 0; j < 64; ++j) mn = fmaxf(mn, Ss[tid][j]);
            float al = __expf(mo - mn);
            float sum = 0.f;
#pragma unroll 8
            for (int j = 0; j < 64; ++j) {
                float pv = __expf(Ss[tid][j] - mn);
                Ss[tid][j] = pv;
                sum += pv;
            }
            mrow[tid] = mn;
            lrow[tid] = lrow[tid] * al + sum;
            arow[tid] = al;
        }
        __syncthreads();

        float al[4];
#pragma unroll
        for (int i = 0; i < 4; ++i) al[i] = arow[ty*4 + i];
#pragma unroll
        for (int i = 0; i < 4; ++i)
#pragma unroll
            for (int j = 0; j < 4; ++j) o[i][j] *= al[i];
#pragma unroll 8
        for (int kk = 0; kk < 64; ++kk) {
            float pr[4], vv[4];
#pragma unroll
            for (int i = 0; i < 4; ++i) { pr[i] = Ss[ty*4 + i][kk]; vv[i] = Vs[kk][tx*4 + i]; }
#pragma unroll
            for (int i = 0; i < 4; ++i)
#pragma unroll
                for (int j = 0; j < 4; ++j) o[i][j] += pr[i] * vv[j];
        }
        __syncthreads();
    }

    float linv[4];
#pragma unroll
    for (int i = 0; i < 4; ++i) linv[i] = 1.f / lrow[ty*4 + i];
#pragma unroll
    for (int i = 0; i < 4; ++i) {
        long gtok = tok0 + base_local + (long)(qt * 64 + ty * 4 + i) * stride;
        size_t off = (size_t)gtok * DMODEL + h * 64 + tx * 4;
#pragma unroll
        for (int j = 0; j < 4; ++j) {
            float val = o[i][j] * linv[i];
            unsigned short hb = f2bf(val);
            aoh[off + j] = hb;
            aol[off + j] = f2bf(val - bf2f(hb));
        }
    }
}

// ---------------------------------------------------------------------------
// out = (attn_br0(x) + attn_br1(x)) / 3,  QKV in 2 chunks of 8192 tokens
// (chunk == batch row, so segments never cross a chunk boundary).
// ws (245 MB): xh,xl | wqh,wql | woh,wol | qkvc [8192x3072]f32 | aoh,aol
// ---------------------------------------------------------------------------
extern "C" void kernel_launch(void* const* d_in, const int* in_sizes, int n_in,
                              void* d_out, int out_size, void* d_ws, size_t ws_size,
                              hipStream_t stream) {
    const float* x    = (const float*)d_in[0];
    const float* Wqkv = (const float*)d_in[1];
    const float* bqkv = (const float*)d_in[2];
    const float* Wout = (const float*)d_in[3];
    const float* bout = (const float*)d_in[4];
    float* out = (float*)d_out;

    char* wp = (char*)d_ws;
    ushort_t* xh  = (ushort_t*)wp; wp += (size_t)TOK * DMODEL * 2;
    ushort_t* xl  = (ushort_t*)wp; wp += (size_t)TOK * DMODEL * 2;
    ushort_t* wqh = (ushort_t*)wp; wp += (size_t)H3 * DMODEL * 2;
    ushort_t* wql = (ushort_t*)wp; wp += (size_t)H3 * DMODEL * 2;
    ushort_t* woh = (ushort_t*)wp; wp += (size_t)DMODEL * DMODEL * 2;
    ushort_t* wol = (ushort_t*)wp; wp += (size_t)DMODEL * DMODEL * 2;
    float*    qkvc = (float*)wp;   wp += (size_t)CHUNK * H3 * 4;
    ushort_t* aoh = (ushort_t*)wp; wp += (size_t)TOK * DMODEL * 2;
    ushort_t* aol = (ushort_t*)wp;

    dim3 blk(256);
    const float third = 1.0f / 3.0f;

    {   // split x once
        int n4 = TOK * DMODEL / 4;
        split_f32<<<(n4 + 255) / 256, blk, 0, stream>>>(x, xh, xl, n4);
    }

    for (int br = 0; br < 2; ++br) {
        const int stride = (br == 0) ? 1 : 2;
        {   // split this branch's weights
            int n4q = H3 * DMODEL / 4;
            split_f32<<<(n4q + 255) / 256, blk, 0, stream>>>(
                Wqkv + (size_t)br * H3 * DMODEL, wqh, wql, n4q);
            int n4o = DMODEL * DMODEL / 4;
            split_f32<<<(n4o + 255) / 256, blk, 0, stream>>>(
                Wout + (size_t)br * DMODEL * DMODEL, woh, wol, n4o);
        }
        for (int c = 0; c < TOK / CHUNK; ++c) {
            gemm_split_nt<<<dim3(H3 / 128, CHUNK / 128), blk, 0, stream>>>(
                xh + (size_t)c * CHUNK * DMODEL, xl + (size_t)c * CHUNK * DMODEL,
                wqh, wql, bqkv + br * H3, qkvc,
                CHUNK, H3, DMODEL, 1.0f, 0);
            attn_seg<<<dim3(8, 16, 16), blk, 0, stream>>>(
                qkvc, aoh, aol, stride, (long)c * CHUNK);
        }
        gemm_split_nt<<<dim3(DMODEL / 128, TOK / 128), blk, 0, stream>>>(
            aoh, aol, woh, wol, bout + br * DMODEL, out,
            TOK, DMODEL, DMODEL, third, br);
    }
}